// Round 9
// baseline (2825.050 us; speedup 1.0000x reference)
//
#include <hip/hip_runtime.h>

#define KITER 16
#define NBKT 512   // max buckets (bucket = 256 target nodes); n <= 131072

typedef __attribute__((ext_vector_type(8))) short short8;
typedef __attribute__((ext_vector_type(4))) float f32x4;

__device__ __forceinline__ unsigned short f2bf(float f) {
    unsigned int u = __float_as_uint(f);
    u = (u + 0x7fffu + ((u >> 16) & 1u)) >> 16;
    return (unsigned short)u;
}
__device__ __forceinline__ float bf2f(unsigned short h) {
    return __uint_as_float(((unsigned int)h) << 16);
}
__device__ __forceinline__ float ulo(unsigned int d) {   // low bf16 -> f32
    return __uint_as_float(d << 16);
}
__device__ __forceinline__ float uhi(unsigned int d) {   // high bf16 -> f32
    return __uint_as_float(d & 0xffff0000u);
}

// ---------------------------------------------------------------- init
__global__ void k_init(int* bktcnt, int* flag) {
    int i = blockIdx.x * blockDim.x + threadIdx.x;
    if (i < NBKT) bktcnt[i] = 0;
    if (i == 0) *flag = 1;
}

// Detect int64 vs int32 edge_index
__global__ void k_detect(const int* ew, int e, int* flag) {
    int t = blockIdx.x * blockDim.x + threadIdx.x;
    if (t < 512 && t < e) {
        if (ew[2 * t + 1] != 0) atomicAnd(flag, 0);
    }
}

// ---------------------------------------------------------------- bucket histogram (LDS-staged)
__global__ __launch_bounds__(256) void k_bhist(const void* eptr, int E, const int* flag,
        int* bktcnt, int n) {
    __shared__ int h[NBKT];
    const int NB = (n + 255) >> 8;
    for (int i = threadIdx.x; i < NB; i += 256) h[i] = 0;
    __syncthreads();
    const int tid0 = blockIdx.x * 256 + threadIdx.x;
    const int stride = gridDim.x * 256;
    if (*flag) {
        const long long* pc = (const long long*)eptr + E;
        for (int i = tid0; i < E; i += stride) atomicAdd(&h[((int)pc[i]) >> 8], 1);
    } else {
        const int* pc = (const int*)eptr + E;
        for (int i = tid0; i < E; i += stride) atomicAdd(&h[pc[i] >> 8], 1);
    }
    __syncthreads();
    for (int i = threadIdx.x; i < NB; i += 256) if (h[i]) atomicAdd(&bktcnt[i], h[i]);
}

// ---------------------------------------------------------------- scan bucket totals -> bases
__global__ __launch_bounds__(512) void k_bscan(const int* bktcnt, int* bktbase, int* bcur, int n) {
    __shared__ int s[NBKT];
    const int NB = (n + 255) >> 8;
    const int tid = threadIdx.x;
    int v = (tid < NB) ? bktcnt[tid] : 0;
    s[tid] = v;
    __syncthreads();
    for (int off = 1; off < NBKT; off <<= 1) {
        int t = (tid >= off) ? s[tid - off] : 0;
        __syncthreads();
        s[tid] += t;
        __syncthreads();
    }
    int excl = s[tid] - v;
    if (tid < NB) { bktbase[tid] = excl; bcur[tid] = excl; }
    if (tid == NB - 1) bktbase[NB] = s[tid];
}

// ---------------------------------------------------------------- phase A: bucket partition
// ebuf entry: (src << 8) | (c & 255)
__global__ __launch_bounds__(256) void k_bucketA(const void* eptr, int E, const int* flag,
        int* bcur, unsigned int* ebuf, int n) {
    __shared__ int hist[NBKT];
    __shared__ int lbase[NBKT];
    __shared__ int lcur[NBKT];
    const int NB = (n + 255) >> 8;
    const int wg = blockIdx.x, nwg = gridDim.x, tid = threadIdx.x;
    const int s0 = (int)(((long long)E * wg) / nwg);
    const int s1 = (int)(((long long)E * (wg + 1)) / nwg);
    for (int b = tid; b < NB; b += 256) { hist[b] = 0; lcur[b] = 0; }
    __syncthreads();
    const bool w64 = (*flag != 0);
    if (w64) {
        const long long* pc = (const long long*)eptr + E;
        for (int i = s0 + tid; i < s1; i += 256)
            atomicAdd(&hist[((int)pc[i]) >> 8], 1);
    } else {
        const int* pc = (const int*)eptr + E;
        for (int i = s0 + tid; i < s1; i += 256)
            atomicAdd(&hist[pc[i] >> 8], 1);
    }
    __syncthreads();
    for (int b = tid; b < NB; b += 256)
        lbase[b] = hist[b] ? atomicAdd(&bcur[b], hist[b]) : 0;
    __syncthreads();
    if (w64) {
        const long long* ps = (const long long*)eptr;
        const long long* pc = ps + E;
        for (int i = s0 + tid; i < s1; i += 256) {
            int c = (int)pc[i];
            int s = (int)ps[i];
            int b = c >> 8;
            int pos = lbase[b] + atomicAdd(&lcur[b], 1);
            ebuf[pos] = ((unsigned int)s << 8) | (unsigned int)(c & 255);
        }
    } else {
        const int* ps = (const int*)eptr;
        const int* pc = ps + E;
        for (int i = s0 + tid; i < s1; i += 256) {
            int c = pc[i];
            int s = ps[i];
            int b = c >> 8;
            int pos = lbase[b] + atomicAdd(&lcur[b], 1);
            ebuf[pos] = ((unsigned int)s << 8) | (unsigned int)(c & 255);
        }
    }
}

// ---------------------------------------------------------------- phase B: within-bucket CSR + rowptr + dinv
// rec stores src*32 (byte offset of a [node][16] bf16 group row).
__global__ __launch_bounds__(256) void k_bucketB(const unsigned int* ebuf, const int* bktbase,
        int* rowptr, int* rec, float* dinv, int n) {
    __shared__ int cnt[256];
    __shared__ int base[256];
    __shared__ int cur[256];
    const int NB = (n + 255) >> 8;
    const int b = blockIdx.x;
    const int lo = b << 8;
    const int nloc = min(256, n - lo);
    const int tid = threadIdx.x;
    cnt[tid] = 0; cur[tid] = 0;
    __syncthreads();
    const int e0 = bktbase[b], e1 = bktbase[b + 1];
    for (int i = e0 + tid; i < e1; i += 256)
        atomicAdd(&cnt[ebuf[i] & 255u], 1);
    __syncthreads();
    int v = cnt[tid];
    base[tid] = v;
    __syncthreads();
    for (int off = 1; off < 256; off <<= 1) {
        int t = (tid >= off) ? base[tid - off] : 0;
        __syncthreads();
        base[tid] += t;
        __syncthreads();
    }
    int ebase = e0 + base[tid] - v;
    if (tid < nloc) {
        rowptr[lo + tid] = ebase;
        dinv[lo + tid] = 1.0f / sqrtf((float)(v + 1));
    }
    base[tid] = ebase;
    __syncthreads();
    if (b == 0 && tid == 0) rowptr[n] = bktbase[NB];
    for (int i = e0 + tid; i < e1; i += 256) {
        unsigned int q = ebuf[i];
        int cl = (int)(q & 255u);
        int pos = base[cl] + atomicAdd(&cur[cl], 1);
        rec[pos] = (int)((q >> 8) << 5);   // src * 32 bytes (group row)
    }
}

// ---------------------------------------------------------------- W1/W2 -> bf16 MFMA-fragment layout
__global__ void k_wprep(const float* __restrict__ W1, const float* __restrict__ W2,
                        unsigned short* __restrict__ W1f, unsigned short* __restrict__ W2f) {
    int t = blockIdx.x * 256 + threadIdx.x;
    if (t < 65536) {
        int e = t & 7, lane = (t >> 3) & 63, nf = (t >> 9) & 7, kt = t >> 12;
        int k = kt * 32 + 8 * (lane >> 4) + e;
        int nn = nf * 16 + (lane & 15);
        W1f[t] = f2bf(W1[k * 128 + nn]);
    } else if (t < 65536 + 8192) {
        int t2 = t - 65536;
        int e = t2 & 7, lane = (t2 >> 3) & 63, nf = (t2 >> 9) & 3, kt2 = t2 >> 11;
        int k = kt2 * 32 + 8 * (lane >> 4) + e;
        int nn = nf * 16 + (lane & 15);
        W2f[t2] = f2bf(W2[k * 64 + nn]);
    }
}

// ---------------------------------------------------------------- MFMA MLP: v = relu(x@W1+b1)@W2+b2
// Double-buffered X staging; emits ax0/zs0 in group layout [g(4)][node][16].
__global__ __launch_bounds__(256) void k_mlp(const float* __restrict__ x,
        const unsigned short* __restrict__ W1f, const float* __restrict__ b1,
        const unsigned short* __restrict__ W2f, const float* __restrict__ b2,
        const float* __restrict__ dinv,
        unsigned short* __restrict__ ax0, unsigned short* __restrict__ zs0, int n) {
    __shared__ union {
        unsigned short Xs[2][4][64][8];   // 8 KB  (A-frags, double-buffered)
        unsigned short HsP[4][64][40];    // 20 KB (h, padded 80-B rows)
    } sm;

    const int tid  = threadIdx.x;
    const int lane = tid & 63;
    const int wv   = tid >> 6;
    const int bm0  = blockIdx.x * 64;

    const int sr = tid >> 2;
    const int sk = tid & 3;
    const long long srow = (long long)bm0 + sr;
    const bool svalid = srow < n;
    const float* xp = x + srow * 512 + sk * 8;

    f32x4 acc[4][2];
#pragma unroll
    for (int mf = 0; mf < 4; ++mf)
#pragma unroll
        for (int nf = 0; nf < 2; ++nf) acc[mf][nf] = (f32x4){0.f, 0.f, 0.f, 0.f};

    {
        float4 f0 = {0, 0, 0, 0}, f1 = {0, 0, 0, 0};
        if (svalid) { f0 = *(const float4*)(xp); f1 = *(const float4*)(xp + 4); }
        uint4 pk;
        pk.x = (unsigned int)f2bf(f0.x) | ((unsigned int)f2bf(f0.y) << 16);
        pk.y = (unsigned int)f2bf(f0.z) | ((unsigned int)f2bf(f0.w) << 16);
        pk.z = (unsigned int)f2bf(f1.x) | ((unsigned int)f2bf(f1.y) << 16);
        pk.w = (unsigned int)f2bf(f1.z) | ((unsigned int)f2bf(f1.w) << 16);
        *(uint4*)&sm.Xs[0][sr >> 4][(sr & 15) + 16 * sk][0] = pk;
    }
    __syncthreads();

    for (int kt = 0; kt < 16; ++kt) {
        float4 g0 = {0, 0, 0, 0}, g1 = {0, 0, 0, 0};
        if (kt < 15 && svalid) {
            g0 = *(const float4*)(xp + (kt + 1) * 32);
            g1 = *(const float4*)(xp + (kt + 1) * 32 + 4);
        }

        short8 bf[2];
#pragma unroll
        for (int nf = 0; nf < 2; ++nf)
            bf[nf] = *(const short8*)(W1f + (((size_t)kt * 8 + wv * 2 + nf) * 64 + lane) * 8);
#pragma unroll
        for (int mf = 0; mf < 4; ++mf) {
            short8 af = *(const short8*)&sm.Xs[kt & 1][mf][lane][0];
#pragma unroll
            for (int nf = 0; nf < 2; ++nf)
                acc[mf][nf] = __builtin_amdgcn_mfma_f32_16x16x32_bf16(af, bf[nf], acc[mf][nf], 0, 0, 0);
        }

        if (kt < 15) {
            uint4 pk;
            pk.x = (unsigned int)f2bf(g0.x) | ((unsigned int)f2bf(g0.y) << 16);
            pk.y = (unsigned int)f2bf(g0.z) | ((unsigned int)f2bf(g0.w) << 16);
            pk.z = (unsigned int)f2bf(g1.x) | ((unsigned int)f2bf(g1.y) << 16);
            pk.w = (unsigned int)f2bf(g1.z) | ((unsigned int)f2bf(g1.w) << 16);
            *(uint4*)&sm.Xs[(kt + 1) & 1][sr >> 4][(sr & 15) + 16 * sk][0] = pk;
        }
        __syncthreads();
    }

    const int c0 = wv * 32 + (lane & 15);
    const float b1v0 = b1[c0];
    const float b1v1 = b1[c0 + 16];
#pragma unroll
    for (int mf = 0; mf < 4; ++mf) {
#pragma unroll
        for (int nf = 0; nf < 2; ++nf) {
            float bb = nf ? b1v1 : b1v0;
            int kk = nf * 16 + (lane & 15);
#pragma unroll
            for (int r = 0; r < 4; ++r) {
                int row = mf * 16 + 4 * (lane >> 4) + r;
                float h = fmaxf(acc[mf][nf][r] + bb, 0.0f);
                sm.HsP[wv][row][kk] = f2bf(h);
            }
        }
    }
    __syncthreads();

    f32x4 acc2[4];
#pragma unroll
    for (int mf = 0; mf < 4; ++mf) acc2[mf] = (f32x4){0.f, 0.f, 0.f, 0.f};
#pragma unroll
    for (int kt2 = 0; kt2 < 4; ++kt2) {
        short8 bf2 = *(const short8*)(W2f + (((size_t)kt2 * 4 + wv) * 64 + lane) * 8);
#pragma unroll
        for (int mf = 0; mf < 4; ++mf) {
            short8 af2 = *(const short8*)&sm.HsP[kt2][mf * 16 + (lane & 15)][8 * (lane >> 4)];
            acc2[mf] = __builtin_amdgcn_mfma_f32_16x16x32_bf16(af2, bf2, acc2[mf], 0, 0, 0);
        }
    }

    // channel oc = wv*16 + (lane&15) -> group wv, idx lane&15 (contiguous 16-lane runs)
    const int oc16 = lane & 15;
    const float bo = b2[wv * 16 + oc16];
    const size_t goff = (size_t)wv * n * 16;
#pragma unroll
    for (int mf = 0; mf < 4; ++mf) {
#pragma unroll
        for (int r = 0; r < 4; ++r) {
            long long row = (long long)bm0 + mf * 16 + 4 * (lane >> 4) + r;
            if (row < n) {
                float v = acc2[mf][r] + bo;
                ax0[goff + row * 16 + oc16] = f2bf(0.1f * v);
                zs0[goff + row * 16 + oc16] = f2bf(dinv[row] * v);
            }
        }
    }
}

// ---------------------------------------------------------------- propagation, 4-group x XCD split, lean loop
// zs layout [g(4)][node][16] bf16 (3.2 MB/group -> per-XCD-L2 resident).
// blockIdx&7 = XCD heuristic: group = xcd&3, node-half = xcd>>2.
// Wave = node: slot = lane>>1 (32 edge slots), hb = lane&1 (16-B half-row).
// One uint4 gather covers 32 edges; rec (src*32) read as one coalesced dword/32 edges.
template<int LAST>
__global__ __launch_bounds__(256) void k_propg(const unsigned short* __restrict__ zs,
        const unsigned short* __restrict__ ax0, const int* __restrict__ rowptr,
        const int* __restrict__ rec, const float* __restrict__ dinv,
        unsigned short* __restrict__ zso, float* __restrict__ zfout,
        int n, int half) {
    const int bid = blockIdx.x;
    const int xcd = bid & 7;
    const int g   = xcd & 3;
    const int h   = xcd >> 2;
    const int wv  = threadIdx.x >> 6;
    int node = h * half + (bid >> 3) * 4 + wv;
    const int lim = h ? n : half;
    if (node >= lim) return;
    node = __builtin_amdgcn_readfirstlane(node);

    const int lane = threadIdx.x & 63;
    const int slot = lane >> 1;          // 32 edge slots
    const int hbo  = (lane & 1) * 16;    // half-row byte offset
    const char* zgb = (const char*)zs + (size_t)g * n * 32;
    const int e0 = rowptr[node], e1 = rowptr[node + 1];

    f32x4 aA = {0.f, 0.f, 0.f, 0.f};     // even channels of this half
    f32x4 aB = {0.f, 0.f, 0.f, 0.f};     // odd channels

    int e = e0;
    for (; e + 32 <= e1; e += 32) {
        int r = rec[e + slot];
        uint4 d = *(const uint4*)(zgb + (size_t)r + hbo);
        aA.x += ulo(d.x); aB.x += uhi(d.x);
        aA.y += ulo(d.y); aB.y += uhi(d.y);
        aA.z += ulo(d.z); aB.z += uhi(d.z);
        aA.w += ulo(d.w); aB.w += uhi(d.w);
    }
    if (e < e1) {                         // masked tail (<= 31 edges)
        int ei = e + slot;
        int ec = (ei < e1) ? ei : (e1 - 1);
        int r = rec[ec];
        uint4 d = *(const uint4*)(zgb + (size_t)r + hbo);
        float w = (ei < e1) ? 1.f : 0.f;
        aA.x = fmaf(w, ulo(d.x), aA.x); aB.x = fmaf(w, uhi(d.x), aB.x);
        aA.y = fmaf(w, ulo(d.y), aA.y); aB.y = fmaf(w, uhi(d.y), aB.y);
        aA.z = fmaf(w, ulo(d.z), aA.z); aB.z = fmaf(w, uhi(d.z), aB.z);
        aA.w = fmaf(w, ulo(d.w), aA.w); aB.w = fmaf(w, uhi(d.w), aB.w);
    }

    // butterfly over slot bits (lane bits 1..5) -> all lanes hold half-row sums
#pragma unroll
    for (int o = 2; o <= 32; o <<= 1) {
        aA.x += __shfl_xor(aA.x, o, 64);
        aA.y += __shfl_xor(aA.y, o, 64);
        aA.z += __shfl_xor(aA.z, o, 64);
        aA.w += __shfl_xor(aA.w, o, 64);
        aB.x += __shfl_xor(aB.x, o, 64);
        aB.y += __shfl_xor(aB.y, o, 64);
        aB.z += __shfl_xor(aB.z, o, 64);
        aB.w += __shfl_xor(aB.w, o, 64);
    }

    // self loop
    uint4 ds = *(const uint4*)(zgb + (size_t)node * 32 + hbo);
    aA.x += ulo(ds.x); aB.x += uhi(ds.x);
    aA.y += ulo(ds.y); aB.y += uhi(ds.y);
    aA.z += ulo(ds.z); aB.z += uhi(ds.z);
    aA.w += ulo(ds.w); aB.w += uhi(ds.w);

    const float dv = dinv[node];
    uint4 da = *(const uint4*)((const char*)ax0 + (size_t)g * n * 32 + (size_t)node * 32 + hbo);
    float z0 = 0.9f * (dv * aA.x) + ulo(da.x);
    float z1 = 0.9f * (dv * aB.x) + uhi(da.x);
    float z2 = 0.9f * (dv * aA.y) + ulo(da.y);
    float z3 = 0.9f * (dv * aB.y) + uhi(da.y);
    float z4 = 0.9f * (dv * aA.z) + ulo(da.z);
    float z5 = 0.9f * (dv * aB.z) + uhi(da.z);
    float z6 = 0.9f * (dv * aA.w) + ulo(da.w);
    float z7 = 0.9f * (dv * aB.w) + uhi(da.w);

    if (slot == 0) {                      // lanes 0 (ch 0-7) and 1 (ch 8-15)
        if (LAST) {
            float4 o0 = {z0, z1, z2, z3};
            float4 o1 = {z4, z5, z6, z7};
            float* dst = zfout + (size_t)node * 64 + g * 16 + (lane & 1) * 8;
            *(float4*)dst = o0;
            *(float4*)(dst + 4) = o1;
        } else {
            uint4 pk;
            pk.x = (unsigned int)f2bf(dv * z0) | ((unsigned int)f2bf(dv * z1) << 16);
            pk.y = (unsigned int)f2bf(dv * z2) | ((unsigned int)f2bf(dv * z3) << 16);
            pk.z = (unsigned int)f2bf(dv * z4) | ((unsigned int)f2bf(dv * z5) << 16);
            pk.w = (unsigned int)f2bf(dv * z6) | ((unsigned int)f2bf(dv * z7) << 16);
            *(uint4*)((char*)zso + (size_t)g * n * 32 + (size_t)node * 32 + hbo) = pk;
        }
    }
}

// ---------------------------------------------------------------- log_softmax in place (row = wave)
__global__ __launch_bounds__(256) void k_lsm(float* z, int n) {
    int node = blockIdx.x * 4 + (threadIdx.x >> 6);
    if (node >= n) return;
    int lane = threadIdx.x & 63;
    long long base = ((long long)node << 6) + lane;
    float v = z[base];
    float m = v;
#pragma unroll
    for (int o = 32; o >= 1; o >>= 1) m = fmaxf(m, __shfl_xor(m, o, 64));
    float e = expf(v - m);
    float s = e;
#pragma unroll
    for (int o = 32; o >= 1; o >>= 1) s += __shfl_xor(s, o, 64);
    z[base] = v - m - logf(s);
}

// ---------------------------------------------------------------- launch
extern "C" void kernel_launch(void* const* d_in, const int* in_sizes, int n_in,
                              void* d_out, int out_size, void* d_ws, size_t ws_size,
                              hipStream_t stream) {
    const float* x  = (const float*)d_in[0];
    const void*  ei = d_in[1];
    const float* W1 = (const float*)d_in[2];
    const float* b1 = (const float*)d_in[3];
    const float* W2 = (const float*)d_in[4];
    const float* b2 = (const float*)d_in[5];
    float* out = (float*)d_out;

    const int n = in_sizes[0] / 512;
    const int E = in_sizes[1] / 2;
    const int NB = (n + 255) >> 8;

    char* p = (char*)d_ws;
    auto alloc = [&](size_t bytes) {
        void* r = (void*)p;
        p += (bytes + 255) & ~(size_t)255;
        return r;
    };
    int*   rowptr  = (int*)alloc((size_t)(n + 1) * 4);
    int*   flag    = (int*)alloc(4);
    int*   bktcnt  = (int*)alloc(NBKT * 4);
    int*   bktbase = (int*)alloc((NBKT + 1) * 4);
    int*   bcur    = (int*)alloc(NBKT * 4);
    float* dinv    = (float*)alloc((size_t)n * 4);
    int*   rec     = (int*)alloc((size_t)E * 4);
    unsigned int* ebuf = (unsigned int*)alloc((size_t)E * 4);
    unsigned short* ax0 = (unsigned short*)alloc((size_t)n * 64 * 2);
    unsigned short* zsA = (unsigned short*)alloc((size_t)n * 64 * 2);
    unsigned short* zsB = (unsigned short*)alloc((size_t)n * 64 * 2);
    unsigned short* W1f = (unsigned short*)alloc(65536 * 2);
    unsigned short* W2f = (unsigned short*)alloc(8192 * 2);

    k_init<<<2, 256, 0, stream>>>(bktcnt, flag);
    k_detect<<<2, 256, 0, stream>>>((const int*)ei, E, flag);
    k_wprep<<<(65536 + 8192 + 255) / 256, 256, 0, stream>>>(W1, W2, W1f, W2f);
    k_bhist<<<512, 256, 0, stream>>>(ei, E, flag, bktcnt, n);
    k_bscan<<<1, 512, 0, stream>>>(bktcnt, bktbase, bcur, n);
    k_bucketA<<<512, 256, 0, stream>>>(ei, E, flag, bcur, ebuf, n);
    k_bucketB<<<NB, 256, 0, stream>>>(ebuf, bktbase, rowptr, rec, dinv, n);
    k_mlp<<<(n + 63) / 64, 256, 0, stream>>>(x, W1f, b1, W2f, b2, dinv, ax0, zsA, n);

    const int half = (n + 1) / 2;
    const int grid = 8 * ((half + 3) / 4);

    const unsigned short* zi = zsA;
    unsigned short* zo = zsB;
    for (int it = 0; it < KITER - 1; ++it) {
        k_propg<0><<<grid, 256, 0, stream>>>(zi, ax0, rowptr, rec, dinv, zo, nullptr, n, half);
        const unsigned short* t = zi; zi = zo; zo = (unsigned short*)t;
    }
    k_propg<1><<<grid, 256, 0, stream>>>(zi, ax0, rowptr, rec, dinv, nullptr, out, n, half);
    k_lsm<<<(n + 3) / 4, 256, 0, stream>>>(out, n);
}

// Round 10
// 1166.698 us; speedup vs baseline: 2.4214x; 2.4214x over previous
//
#include <hip/hip_runtime.h>

#define KITER 16
#define NBKT 512   // max buckets (bucket = 256 target nodes); n <= 131072
#define FP8_SCALE 16.0f
#define FP8_INV   0.0625f

typedef __attribute__((ext_vector_type(8))) short short8;
typedef __attribute__((ext_vector_type(4))) float f32x4;
typedef __attribute__((ext_vector_type(2))) float f32x2;

__device__ __forceinline__ unsigned short f2bf(float f) {
    unsigned int u = __float_as_uint(f);
    u = (u + 0x7fffu + ((u >> 16) & 1u)) >> 16;
    return (unsigned short)u;
}
__device__ __forceinline__ float ulo(unsigned int d) {   // low bf16 -> f32
    return __uint_as_float(d << 16);
}
__device__ __forceinline__ float uhi(unsigned int d) {   // high bf16 -> f32
    return __uint_as_float(d & 0xffff0000u);
}

// ---------------------------------------------------------------- init
__global__ void k_init(int* bktcnt, int* flag) {
    int i = blockIdx.x * blockDim.x + threadIdx.x;
    if (i < NBKT) bktcnt[i] = 0;
    if (i == 0) *flag = 1;
}

// Detect int64 vs int32 edge_index
__global__ void k_detect(const int* ew, int e, int* flag) {
    int t = blockIdx.x * blockDim.x + threadIdx.x;
    if (t < 512 && t < e) {
        if (ew[2 * t + 1] != 0) atomicAnd(flag, 0);
    }
}

// ---------------------------------------------------------------- bucket histogram (LDS-staged)
__global__ __launch_bounds__(256) void k_bhist(const void* eptr, int E, const int* flag,
        int* bktcnt, int n) {
    __shared__ int h[NBKT];
    const int NB = (n + 255) >> 8;
    for (int i = threadIdx.x; i < NB; i += 256) h[i] = 0;
    __syncthreads();
    const int tid0 = blockIdx.x * 256 + threadIdx.x;
    const int stride = gridDim.x * 256;
    if (*flag) {
        const long long* pc = (const long long*)eptr + E;
        for (int i = tid0; i < E; i += stride) atomicAdd(&h[((int)pc[i]) >> 8], 1);
    } else {
        const int* pc = (const int*)eptr + E;
        for (int i = tid0; i < E; i += stride) atomicAdd(&h[pc[i] >> 8], 1);
    }
    __syncthreads();
    for (int i = threadIdx.x; i < NB; i += 256) if (h[i]) atomicAdd(&bktcnt[i], h[i]);
}

// ---------------------------------------------------------------- scan bucket totals -> bases
__global__ __launch_bounds__(512) void k_bscan(const int* bktcnt, int* bktbase, int* bcur, int n) {
    __shared__ int s[NBKT];
    const int NB = (n + 255) >> 8;
    const int tid = threadIdx.x;
    int v = (tid < NB) ? bktcnt[tid] : 0;
    s[tid] = v;
    __syncthreads();
    for (int off = 1; off < NBKT; off <<= 1) {
        int t = (tid >= off) ? s[tid - off] : 0;
        __syncthreads();
        s[tid] += t;
        __syncthreads();
    }
    int excl = s[tid] - v;
    if (tid < NB) { bktbase[tid] = excl; bcur[tid] = excl; }
    if (tid == NB - 1) bktbase[NB] = s[tid];
}

// ---------------------------------------------------------------- phase A: bucket partition
// ebuf entry: (src << 8) | (c & 255)
__global__ __launch_bounds__(256) void k_bucketA(const void* eptr, int E, const int* flag,
        int* bcur, unsigned int* ebuf, int n) {
    __shared__ int hist[NBKT];
    __shared__ int lbase[NBKT];
    __shared__ int lcur[NBKT];
    const int NB = (n + 255) >> 8;
    const int wg = blockIdx.x, nwg = gridDim.x, tid = threadIdx.x;
    const int s0 = (int)(((long long)E * wg) / nwg);
    const int s1 = (int)(((long long)E * (wg + 1)) / nwg);
    for (int b = tid; b < NB; b += 256) { hist[b] = 0; lcur[b] = 0; }
    __syncthreads();
    const bool w64 = (*flag != 0);
    if (w64) {
        const long long* pc = (const long long*)eptr + E;
        for (int i = s0 + tid; i < s1; i += 256)
            atomicAdd(&hist[((int)pc[i]) >> 8], 1);
    } else {
        const int* pc = (const int*)eptr + E;
        for (int i = s0 + tid; i < s1; i += 256)
            atomicAdd(&hist[pc[i] >> 8], 1);
    }
    __syncthreads();
    for (int b = tid; b < NB; b += 256)
        lbase[b] = hist[b] ? atomicAdd(&bcur[b], hist[b]) : 0;
    __syncthreads();
    if (w64) {
        const long long* ps = (const long long*)eptr;
        const long long* pc = ps + E;
        for (int i = s0 + tid; i < s1; i += 256) {
            int c = (int)pc[i];
            int s = (int)ps[i];
            int b = c >> 8;
            int pos = lbase[b] + atomicAdd(&lcur[b], 1);
            ebuf[pos] = ((unsigned int)s << 8) | (unsigned int)(c & 255);
        }
    } else {
        const int* ps = (const int*)eptr;
        const int* pc = ps + E;
        for (int i = s0 + tid; i < s1; i += 256) {
            int c = pc[i];
            int s = ps[i];
            int b = c >> 8;
            int pos = lbase[b] + atomicAdd(&lcur[b], 1);
            ebuf[pos] = ((unsigned int)s << 8) | (unsigned int)(c & 255);
        }
    }
}

// ---------------------------------------------------------------- phase B: within-bucket CSR + rowptr + dinv
// rec stores src*64 (byte offset of a [node][64] fp8 row).
__global__ __launch_bounds__(256) void k_bucketB(const unsigned int* ebuf, const int* bktbase,
        int* rowptr, int* rec, float* dinv, int n) {
    __shared__ int cnt[256];
    __shared__ int base[256];
    __shared__ int cur[256];
    const int NB = (n + 255) >> 8;
    const int b = blockIdx.x;
    const int lo = b << 8;
    const int nloc = min(256, n - lo);
    const int tid = threadIdx.x;
    cnt[tid] = 0; cur[tid] = 0;
    __syncthreads();
    const int e0 = bktbase[b], e1 = bktbase[b + 1];
    for (int i = e0 + tid; i < e1; i += 256)
        atomicAdd(&cnt[ebuf[i] & 255u], 1);
    __syncthreads();
    int v = cnt[tid];
    base[tid] = v;
    __syncthreads();
    for (int off = 1; off < 256; off <<= 1) {
        int t = (tid >= off) ? base[tid - off] : 0;
        __syncthreads();
        base[tid] += t;
        __syncthreads();
    }
    int ebase = e0 + base[tid] - v;
    if (tid < nloc) {
        rowptr[lo + tid] = ebase;
        dinv[lo + tid] = 1.0f / sqrtf((float)(v + 1));
    }
    base[tid] = ebase;
    __syncthreads();
    if (b == 0 && tid == 0) rowptr[n] = bktbase[NB];
    for (int i = e0 + tid; i < e1; i += 256) {
        unsigned int q = ebuf[i];
        int cl = (int)(q & 255u);
        int pos = base[cl] + atomicAdd(&cur[cl], 1);
        rec[pos] = (int)((q >> 8) << 6);   // src * 64 bytes (fp8 row)
    }
}

// ---------------------------------------------------------------- W1/W2 -> bf16 MFMA-fragment layout
__global__ void k_wprep(const float* __restrict__ W1, const float* __restrict__ W2,
                        unsigned short* __restrict__ W1f, unsigned short* __restrict__ W2f) {
    int t = blockIdx.x * 256 + threadIdx.x;
    if (t < 65536) {
        int e = t & 7, lane = (t >> 3) & 63, nf = (t >> 9) & 7, kt = t >> 12;
        int k = kt * 32 + 8 * (lane >> 4) + e;
        int nn = nf * 16 + (lane & 15);
        W1f[t] = f2bf(W1[k * 128 + nn]);
    } else if (t < 65536 + 8192) {
        int t2 = t - 65536;
        int e = t2 & 7, lane = (t2 >> 3) & 63, nf = (t2 >> 9) & 3, kt2 = t2 >> 11;
        int k = kt2 * 32 + 8 * (lane >> 4) + e;
        int nn = nf * 16 + (lane & 15);
        W2f[t2] = f2bf(W2[k * 64 + nn]);
    }
}

// ---------------------------------------------------------------- MFMA MLP: v = relu(x@W1+b1)@W2+b2
// Double-buffered X staging; emits ax0 = bf16(0.1*v) and zs0 = fp8(16*dinv*v).
__global__ __launch_bounds__(256) void k_mlp(const float* __restrict__ x,
        const unsigned short* __restrict__ W1f, const float* __restrict__ b1,
        const unsigned short* __restrict__ W2f, const float* __restrict__ b2,
        const float* __restrict__ dinv,
        unsigned short* __restrict__ ax0, unsigned char* __restrict__ zs0, int n) {
    __shared__ union {
        unsigned short Xs[2][4][64][8];   // 8 KB  (A-frags, double-buffered)
        unsigned short HsP[4][64][40];    // 20 KB (h, padded 80-B rows)
    } sm;

    const int tid  = threadIdx.x;
    const int lane = tid & 63;
    const int wv   = tid >> 6;
    const int bm0  = blockIdx.x * 64;

    const int sr = tid >> 2;
    const int sk = tid & 3;
    const long long srow = (long long)bm0 + sr;
    const bool svalid = srow < n;
    const float* xp = x + srow * 512 + sk * 8;

    f32x4 acc[4][2];
#pragma unroll
    for (int mf = 0; mf < 4; ++mf)
#pragma unroll
        for (int nf = 0; nf < 2; ++nf) acc[mf][nf] = (f32x4){0.f, 0.f, 0.f, 0.f};

    {
        float4 f0 = {0, 0, 0, 0}, f1 = {0, 0, 0, 0};
        if (svalid) { f0 = *(const float4*)(xp); f1 = *(const float4*)(xp + 4); }
        uint4 pk;
        pk.x = (unsigned int)f2bf(f0.x) | ((unsigned int)f2bf(f0.y) << 16);
        pk.y = (unsigned int)f2bf(f0.z) | ((unsigned int)f2bf(f0.w) << 16);
        pk.z = (unsigned int)f2bf(f1.x) | ((unsigned int)f2bf(f1.y) << 16);
        pk.w = (unsigned int)f2bf(f1.z) | ((unsigned int)f2bf(f1.w) << 16);
        *(uint4*)&sm.Xs[0][sr >> 4][(sr & 15) + 16 * sk][0] = pk;
    }
    __syncthreads();

    for (int kt = 0; kt < 16; ++kt) {
        float4 g0 = {0, 0, 0, 0}, g1 = {0, 0, 0, 0};
        if (kt < 15 && svalid) {
            g0 = *(const float4*)(xp + (kt + 1) * 32);
            g1 = *(const float4*)(xp + (kt + 1) * 32 + 4);
        }

        short8 bf[2];
#pragma unroll
        for (int nf = 0; nf < 2; ++nf)
            bf[nf] = *(const short8*)(W1f + (((size_t)kt * 8 + wv * 2 + nf) * 64 + lane) * 8);
#pragma unroll
        for (int mf = 0; mf < 4; ++mf) {
            short8 af = *(const short8*)&sm.Xs[kt & 1][mf][lane][0];
#pragma unroll
            for (int nf = 0; nf < 2; ++nf)
                acc[mf][nf] = __builtin_amdgcn_mfma_f32_16x16x32_bf16(af, bf[nf], acc[mf][nf], 0, 0, 0);
        }

        if (kt < 15) {
            uint4 pk;
            pk.x = (unsigned int)f2bf(g0.x) | ((unsigned int)f2bf(g0.y) << 16);
            pk.y = (unsigned int)f2bf(g0.z) | ((unsigned int)f2bf(g0.w) << 16);
            pk.z = (unsigned int)f2bf(g1.x) | ((unsigned int)f2bf(g1.y) << 16);
            pk.w = (unsigned int)f2bf(g1.z) | ((unsigned int)f2bf(g1.w) << 16);
            *(uint4*)&sm.Xs[(kt + 1) & 1][sr >> 4][(sr & 15) + 16 * sk][0] = pk;
        }
        __syncthreads();
    }

    const int c0 = wv * 32 + (lane & 15);
    const float b1v0 = b1[c0];
    const float b1v1 = b1[c0 + 16];
#pragma unroll
    for (int mf = 0; mf < 4; ++mf) {
#pragma unroll
        for (int nf = 0; nf < 2; ++nf) {
            float bb = nf ? b1v1 : b1v0;
            int kk = nf * 16 + (lane & 15);
#pragma unroll
            for (int r = 0; r < 4; ++r) {
                int row = mf * 16 + 4 * (lane >> 4) + r;
                float h = fmaxf(acc[mf][nf][r] + bb, 0.0f);
                sm.HsP[wv][row][kk] = f2bf(h);
            }
        }
    }
    __syncthreads();

    f32x4 acc2[4];
#pragma unroll
    for (int mf = 0; mf < 4; ++mf) acc2[mf] = (f32x4){0.f, 0.f, 0.f, 0.f};
#pragma unroll
    for (int kt2 = 0; kt2 < 4; ++kt2) {
        short8 bf2 = *(const short8*)(W2f + (((size_t)kt2 * 4 + wv) * 64 + lane) * 8);
#pragma unroll
        for (int mf = 0; mf < 4; ++mf) {
            short8 af2 = *(const short8*)&sm.HsP[kt2][mf * 16 + (lane & 15)][8 * (lane >> 4)];
            acc2[mf] = __builtin_amdgcn_mfma_f32_16x16x32_bf16(af2, bf2, acc2[mf], 0, 0, 0);
        }
    }

    const int oc = wv * 16 + (lane & 15);
    const float bo = b2[oc];
#pragma unroll
    for (int mf = 0; mf < 4; ++mf) {
#pragma unroll
        for (int r = 0; r < 4; ++r) {
            long long row = (long long)bm0 + mf * 16 + 4 * (lane >> 4) + r;
            if (row < n) {
                float v = acc2[mf][r] + bo;
                ax0[row * 64 + oc] = f2bf(0.1f * v);
                float zv = dinv[row] * v * FP8_SCALE;
                unsigned int eb = __builtin_amdgcn_cvt_pk_fp8_f32(zv, zv, 0u, false) & 0xffu;
                zs0[row * 64 + oc] = (unsigned char)eb;
            }
        }
    }
}

// ---------------------------------------------------------------- propagation, fp8 state
// zs = fp8(16*dinv*z), layout [node][64] = 64 B rows. Wave = node.
// slot = lane>>3 (8 edge slots); lane&7 = 8-channel group (8 B).
// One uint2 gather covers 8 edges x 64 B row, coalesced. HW fp8->f32 cvt.
// LAST=1 fuses log_softmax, writes fp32 out.
template<int LAST>
__global__ __launch_bounds__(256) void k_prop(const unsigned char* __restrict__ zs,
        const unsigned short* __restrict__ ax0, const int* __restrict__ rowptr,
        const int* __restrict__ rec, const float* __restrict__ dinv,
        unsigned char* __restrict__ zso, float* __restrict__ zfout, int n) {
    int node = __builtin_amdgcn_readfirstlane(blockIdx.x * 4 + (threadIdx.x >> 6));
    if (node >= n) return;
    const int lane = threadIdx.x & 63;
    const int slot = lane >> 3;        // 8 edge slots
    const int cb   = (lane & 7) * 8;   // channel-group byte offset within 64-B row
    const int e0 = rowptr[node], e1 = rowptr[node + 1];

    float a0 = 0.f, a1 = 0.f, a2 = 0.f, a3 = 0.f;
    float a4 = 0.f, a5 = 0.f, a6 = 0.f, a7 = 0.f;

    int e = e0;
    for (; e + 8 <= e1; e += 8) {
        int r = rec[e + slot];
        uint2 d = *(const uint2*)(zs + (size_t)r + cb);
        f32x2 p0 = __builtin_amdgcn_cvt_pk_f32_fp8(d.x, false);
        f32x2 p1 = __builtin_amdgcn_cvt_pk_f32_fp8(d.x, true);
        f32x2 p2 = __builtin_amdgcn_cvt_pk_f32_fp8(d.y, false);
        f32x2 p3 = __builtin_amdgcn_cvt_pk_f32_fp8(d.y, true);
        a0 += p0.x; a1 += p0.y; a2 += p1.x; a3 += p1.y;
        a4 += p2.x; a5 += p2.y; a6 += p3.x; a7 += p3.y;
    }
    if (e < e1) {                       // masked tail (<= 7 edges)
        int ei = e + slot;
        int ec = (ei < e1) ? ei : (e1 - 1);
        int r = rec[ec];
        uint2 d = *(const uint2*)(zs + (size_t)r + cb);
        float w = (ei < e1) ? 1.f : 0.f;
        f32x2 p0 = __builtin_amdgcn_cvt_pk_f32_fp8(d.x, false);
        f32x2 p1 = __builtin_amdgcn_cvt_pk_f32_fp8(d.x, true);
        f32x2 p2 = __builtin_amdgcn_cvt_pk_f32_fp8(d.y, false);
        f32x2 p3 = __builtin_amdgcn_cvt_pk_f32_fp8(d.y, true);
        a0 = fmaf(w, p0.x, a0); a1 = fmaf(w, p0.y, a1);
        a2 = fmaf(w, p1.x, a2); a3 = fmaf(w, p1.y, a3);
        a4 = fmaf(w, p2.x, a4); a5 = fmaf(w, p2.y, a5);
        a6 = fmaf(w, p3.x, a6); a7 = fmaf(w, p3.y, a7);
    }

    // butterfly over slot bits (lane bits 3..5)
#pragma unroll
    for (int o = 8; o <= 32; o <<= 1) {
        a0 += __shfl_xor(a0, o, 64);
        a1 += __shfl_xor(a1, o, 64);
        a2 += __shfl_xor(a2, o, 64);
        a3 += __shfl_xor(a3, o, 64);
        a4 += __shfl_xor(a4, o, 64);
        a5 += __shfl_xor(a5, o, 64);
        a6 += __shfl_xor(a6, o, 64);
        a7 += __shfl_xor(a7, o, 64);
    }

    if (slot == 0) {                    // lanes 0..7 hold the full row sums
        // self loop
        uint2 ds = *(const uint2*)(zs + (size_t)node * 64 + cb);
        f32x2 s0 = __builtin_amdgcn_cvt_pk_f32_fp8(ds.x, false);
        f32x2 s1 = __builtin_amdgcn_cvt_pk_f32_fp8(ds.x, true);
        f32x2 s2 = __builtin_amdgcn_cvt_pk_f32_fp8(ds.y, false);
        f32x2 s3 = __builtin_amdgcn_cvt_pk_f32_fp8(ds.y, true);
        a0 += s0.x; a1 += s0.y; a2 += s1.x; a3 += s1.y;
        a4 += s2.x; a5 += s2.y; a6 += s3.x; a7 += s3.y;

        const float dv = dinv[node];
        const float c = 0.9f * dv * FP8_INV;
        uint4 da = *(const uint4*)((const char*)ax0 + (size_t)node * 128 + cb * 2);
        float z0 = fmaf(c, a0, ulo(da.x));
        float z1 = fmaf(c, a1, uhi(da.x));
        float z2 = fmaf(c, a2, ulo(da.y));
        float z3 = fmaf(c, a3, uhi(da.y));
        float z4 = fmaf(c, a4, ulo(da.z));
        float z5 = fmaf(c, a5, uhi(da.z));
        float z6 = fmaf(c, a6, ulo(da.w));
        float z7 = fmaf(c, a7, uhi(da.w));

        if (LAST) {
            float m = fmaxf(fmaxf(fmaxf(z0, z1), fmaxf(z2, z3)),
                            fmaxf(fmaxf(z4, z5), fmaxf(z6, z7)));
            m = fmaxf(m, __shfl_xor(m, 1, 64));
            m = fmaxf(m, __shfl_xor(m, 2, 64));
            m = fmaxf(m, __shfl_xor(m, 4, 64));
            float s = expf(z0 - m) + expf(z1 - m) + expf(z2 - m) + expf(z3 - m)
                    + expf(z4 - m) + expf(z5 - m) + expf(z6 - m) + expf(z7 - m);
            s += __shfl_xor(s, 1, 64);
            s += __shfl_xor(s, 2, 64);
            s += __shfl_xor(s, 4, 64);
            float ls = m + logf(s);
            float* dst = zfout + (size_t)node * 64 + cb;
            float4 o0 = {z0 - ls, z1 - ls, z2 - ls, z3 - ls};
            float4 o1 = {z4 - ls, z5 - ls, z6 - ls, z7 - ls};
            *(float4*)dst = o0;
            *(float4*)(dst + 4) = o1;
        } else {
            const float enc = FP8_SCALE * dv;
            unsigned int lo = __builtin_amdgcn_cvt_pk_fp8_f32(enc * z0, enc * z1, 0u, false);
            lo = __builtin_amdgcn_cvt_pk_fp8_f32(enc * z2, enc * z3, lo, true);
            unsigned int hi = __builtin_amdgcn_cvt_pk_fp8_f32(enc * z4, enc * z5, 0u, false);
            hi = __builtin_amdgcn_cvt_pk_fp8_f32(enc * z6, enc * z7, hi, true);
            uint2 pk; pk.x = lo; pk.y = hi;
            *(uint2*)(zso + (size_t)node * 64 + cb) = pk;
        }
    }
}

// ---------------------------------------------------------------- launch
extern "C" void kernel_launch(void* const* d_in, const int* in_sizes, int n_in,
                              void* d_out, int out_size, void* d_ws, size_t ws_size,
                              hipStream_t stream) {
    const float* x  = (const float*)d_in[0];
    const void*  ei = d_in[1];
    const float* W1 = (const float*)d_in[2];
    const float* b1 = (const float*)d_in[3];
    const float* W2 = (const float*)d_in[4];
    const float* b2 = (const float*)d_in[5];
    float* out = (float*)d_out;

    const int n = in_sizes[0] / 512;
    const int E = in_sizes[1] / 2;
    const int NB = (n + 255) >> 8;

    char* p = (char*)d_ws;
    auto alloc = [&](size_t bytes) {
        void* r = (void*)p;
        p += (bytes + 255) & ~(size_t)255;
        return r;
    };
    int*   rowptr  = (int*)alloc((size_t)(n + 1) * 4);
    int*   flag    = (int*)alloc(4);
    int*   bktcnt  = (int*)alloc(NBKT * 4);
    int*   bktbase = (int*)alloc((NBKT + 1) * 4);
    int*   bcur    = (int*)alloc(NBKT * 4);
    float* dinv    = (float*)alloc((size_t)n * 4);
    int*   rec     = (int*)alloc((size_t)E * 4);
    unsigned int* ebuf = (unsigned int*)alloc((size_t)E * 4);
    unsigned short* ax0 = (unsigned short*)alloc((size_t)n * 64 * 2);
    unsigned char* zsA = (unsigned char*)alloc((size_t)n * 64);
    unsigned char* zsB = (unsigned char*)alloc((size_t)n * 64);
    unsigned short* W1f = (unsigned short*)alloc(65536 * 2);
    unsigned short* W2f = (unsigned short*)alloc(8192 * 2);

    k_init<<<2, 256, 0, stream>>>(bktcnt, flag);
    k_detect<<<2, 256, 0, stream>>>((const int*)ei, E, flag);
    k_wprep<<<(65536 + 8192 + 255) / 256, 256, 0, stream>>>(W1, W2, W1f, W2f);
    k_bhist<<<512, 256, 0, stream>>>(ei, E, flag, bktcnt, n);
    k_bscan<<<1, 512, 0, stream>>>(bktcnt, bktbase, bcur, n);
    k_bucketA<<<512, 256, 0, stream>>>(ei, E, flag, bcur, ebuf, n);
    k_bucketB<<<NB, 256, 0, stream>>>(ebuf, bktbase, rowptr, rec, dinv, n);
    k_mlp<<<(n + 63) / 64, 256, 0, stream>>>(x, W1f, b1, W2f, b2, dinv, ax0, zsA, n);

    const unsigned char* zi = zsA;
    unsigned char* zo = zsB;
    for (int it = 0; it < KITER - 1; ++it) {
        k_prop<0><<<(n + 3) / 4, 256, 0, stream>>>(zi, ax0, rowptr, rec, dinv, zo, nullptr, n);
        const unsigned char* t = zi; zi = zo; zo = (unsigned char*)t;
    }
    k_prop<1><<<(n + 3) / 4, 256, 0, stream>>>(zi, ax0, rowptr, rec, dinv, nullptr, out, n);
}

// Round 11
// 938.947 us; speedup vs baseline: 3.0087x; 1.2426x over previous
//
#include <hip/hip_runtime.h>

#define KITER 16
#define NBKT 512   // max buckets (bucket = 256 target nodes); n <= 131072
#define FP8_SCALE 16.0f
#define FP8_INV   0.0625f

typedef __attribute__((ext_vector_type(8))) short short8;
typedef __attribute__((ext_vector_type(4))) float f32x4;
typedef __attribute__((ext_vector_type(2))) float f32x2;

__device__ __forceinline__ unsigned short f2bf(float f) {
    unsigned int u = __float_as_uint(f);
    u = (u + 0x7fffu + ((u >> 16) & 1u)) >> 16;
    return (unsigned short)u;
}
__device__ __forceinline__ float ulo(unsigned int d) {   // low bf16 -> f32
    return __uint_as_float(d << 16);
}
__device__ __forceinline__ float uhi(unsigned int d) {   // high bf16 -> f32
    return __uint_as_float(d & 0xffff0000u);
}

// ---------------------------------------------------------------- init
__global__ void k_init(int* bktcnt, int* flag) {
    int i = blockIdx.x * blockDim.x + threadIdx.x;
    if (i < NBKT) bktcnt[i] = 0;
    if (i == 0) *flag = 1;
}

// Detect int64 vs int32 edge_index
__global__ void k_detect(const int* ew, int e, int* flag) {
    int t = blockIdx.x * blockDim.x + threadIdx.x;
    if (t < 512 && t < e) {
        if (ew[2 * t + 1] != 0) atomicAnd(flag, 0);
    }
}

// ---------------------------------------------------------------- bucket histogram (LDS-staged)
__global__ __launch_bounds__(256) void k_bhist(const void* eptr, int E, const int* flag,
        int* bktcnt, int n) {
    __shared__ int h[NBKT];
    const int NB = (n + 255) >> 8;
    for (int i = threadIdx.x; i < NB; i += 256) h[i] = 0;
    __syncthreads();
    const int tid0 = blockIdx.x * 256 + threadIdx.x;
    const int stride = gridDim.x * 256;
    if (*flag) {
        const long long* pc = (const long long*)eptr + E;
        for (int i = tid0; i < E; i += stride) atomicAdd(&h[((int)pc[i]) >> 8], 1);
    } else {
        const int* pc = (const int*)eptr + E;
        for (int i = tid0; i < E; i += stride) atomicAdd(&h[pc[i] >> 8], 1);
    }
    __syncthreads();
    for (int i = threadIdx.x; i < NB; i += 256) if (h[i]) atomicAdd(&bktcnt[i], h[i]);
}

// ---------------------------------------------------------------- scan bucket totals -> bases
__global__ __launch_bounds__(512) void k_bscan(const int* bktcnt, int* bktbase, int* bcur, int n) {
    __shared__ int s[NBKT];
    const int NB = (n + 255) >> 8;
    const int tid = threadIdx.x;
    int v = (tid < NB) ? bktcnt[tid] : 0;
    s[tid] = v;
    __syncthreads();
    for (int off = 1; off < NBKT; off <<= 1) {
        int t = (tid >= off) ? s[tid - off] : 0;
        __syncthreads();
        s[tid] += t;
        __syncthreads();
    }
    int excl = s[tid] - v;
    if (tid < NB) { bktbase[tid] = excl; bcur[tid] = excl; }
    if (tid == NB - 1) bktbase[NB] = s[tid];
}

// ---------------------------------------------------------------- phase A: bucket partition
// ebuf entry: (src << 8) | (c & 255)
__global__ __launch_bounds__(256) void k_bucketA(const void* eptr, int E, const int* flag,
        int* bcur, unsigned int* ebuf, int n) {
    __shared__ int hist[NBKT];
    __shared__ int lbase[NBKT];
    __shared__ int lcur[NBKT];
    const int NB = (n + 255) >> 8;
    const int wg = blockIdx.x, nwg = gridDim.x, tid = threadIdx.x;
    const int s0 = (int)(((long long)E * wg) / nwg);
    const int s1 = (int)(((long long)E * (wg + 1)) / nwg);
    for (int b = tid; b < NB; b += 256) { hist[b] = 0; lcur[b] = 0; }
    __syncthreads();
    const bool w64 = (*flag != 0);
    if (w64) {
        const long long* pc = (const long long*)eptr + E;
        for (int i = s0 + tid; i < s1; i += 256)
            atomicAdd(&hist[((int)pc[i]) >> 8], 1);
    } else {
        const int* pc = (const int*)eptr + E;
        for (int i = s0 + tid; i < s1; i += 256)
            atomicAdd(&hist[pc[i] >> 8], 1);
    }
    __syncthreads();
    for (int b = tid; b < NB; b += 256)
        lbase[b] = hist[b] ? atomicAdd(&bcur[b], hist[b]) : 0;
    __syncthreads();
    if (w64) {
        const long long* ps = (const long long*)eptr;
        const long long* pc = ps + E;
        for (int i = s0 + tid; i < s1; i += 256) {
            int c = (int)pc[i];
            int s = (int)ps[i];
            int b = c >> 8;
            int pos = lbase[b] + atomicAdd(&lcur[b], 1);
            ebuf[pos] = ((unsigned int)s << 8) | (unsigned int)(c & 255);
        }
    } else {
        const int* ps = (const int*)eptr;
        const int* pc = ps + E;
        for (int i = s0 + tid; i < s1; i += 256) {
            int c = pc[i];
            int s = ps[i];
            int b = c >> 8;
            int pos = lbase[b] + atomicAdd(&lcur[b], 1);
            ebuf[pos] = ((unsigned int)s << 8) | (unsigned int)(c & 255);
        }
    }
}

// ---------------------------------------------------------------- phase B: within-bucket CSR + rowptr + dinv
// rec stores src*64 (byte offset of a [node][64] fp8 row).
__global__ __launch_bounds__(256) void k_bucketB(const unsigned int* ebuf, const int* bktbase,
        int* rowptr, int* rec, float* dinv, int n) {
    __shared__ int cnt[256];
    __shared__ int base[256];
    __shared__ int cur[256];
    const int NB = (n + 255) >> 8;
    const int b = blockIdx.x;
    const int lo = b << 8;
    const int nloc = min(256, n - lo);
    const int tid = threadIdx.x;
    cnt[tid] = 0; cur[tid] = 0;
    __syncthreads();
    const int e0 = bktbase[b], e1 = bktbase[b + 1];
    for (int i = e0 + tid; i < e1; i += 256)
        atomicAdd(&cnt[ebuf[i] & 255u], 1);
    __syncthreads();
    int v = cnt[tid];
    base[tid] = v;
    __syncthreads();
    for (int off = 1; off < 256; off <<= 1) {
        int t = (tid >= off) ? base[tid - off] : 0;
        __syncthreads();
        base[tid] += t;
        __syncthreads();
    }
    int ebase = e0 + base[tid] - v;
    if (tid < nloc) {
        rowptr[lo + tid] = ebase;
        dinv[lo + tid] = 1.0f / sqrtf((float)(v + 1));
    }
    base[tid] = ebase;
    __syncthreads();
    if (b == 0 && tid == 0) rowptr[n] = bktbase[NB];
    for (int i = e0 + tid; i < e1; i += 256) {
        unsigned int q = ebuf[i];
        int cl = (int)(q & 255u);
        int pos = base[cl] + atomicAdd(&cur[cl], 1);
        rec[pos] = (int)((q >> 8) << 6);   // src * 64 bytes (fp8 row)
    }
}

// ---------------------------------------------------------------- W1/W2 -> bf16 MFMA-fragment layout
__global__ void k_wprep(const float* __restrict__ W1, const float* __restrict__ W2,
                        unsigned short* __restrict__ W1f, unsigned short* __restrict__ W2f) {
    int t = blockIdx.x * 256 + threadIdx.x;
    if (t < 65536) {
        int e = t & 7, lane = (t >> 3) & 63, nf = (t >> 9) & 7, kt = t >> 12;
        int k = kt * 32 + 8 * (lane >> 4) + e;
        int nn = nf * 16 + (lane & 15);
        W1f[t] = f2bf(W1[k * 128 + nn]);
    } else if (t < 65536 + 8192) {
        int t2 = t - 65536;
        int e = t2 & 7, lane = (t2 >> 3) & 63, nf = (t2 >> 9) & 3, kt2 = t2 >> 11;
        int k = kt2 * 32 + 8 * (lane >> 4) + e;
        int nn = nf * 16 + (lane & 15);
        W2f[t2] = f2bf(W2[k * 64 + nn]);
    }
}

// ---------------------------------------------------------------- MFMA MLP: v = relu(x@W1+b1)@W2+b2
// Double-buffered X staging; emits ax0 = bf16(0.1*v) and zs0 = fp8(16*dinv*v).
__global__ __launch_bounds__(256) void k_mlp(const float* __restrict__ x,
        const unsigned short* __restrict__ W1f, const float* __restrict__ b1,
        const unsigned short* __restrict__ W2f, const float* __restrict__ b2,
        const float* __restrict__ dinv,
        unsigned short* __restrict__ ax0, unsigned char* __restrict__ zs0, int n) {
    __shared__ union {
        unsigned short Xs[2][4][64][8];   // 8 KB  (A-frags, double-buffered)
        unsigned short HsP[4][64][40];    // 20 KB (h, padded 80-B rows)
    } sm;

    const int tid  = threadIdx.x;
    const int lane = tid & 63;
    const int wv   = tid >> 6;
    const int bm0  = blockIdx.x * 64;

    const int sr = tid >> 2;
    const int sk = tid & 3;
    const long long srow = (long long)bm0 + sr;
    const bool svalid = srow < n;
    const float* xp = x + srow * 512 + sk * 8;

    f32x4 acc[4][2];
#pragma unroll
    for (int mf = 0; mf < 4; ++mf)
#pragma unroll
        for (int nf = 0; nf < 2; ++nf) acc[mf][nf] = (f32x4){0.f, 0.f, 0.f, 0.f};

    {
        float4 f0 = {0, 0, 0, 0}, f1 = {0, 0, 0, 0};
        if (svalid) { f0 = *(const float4*)(xp); f1 = *(const float4*)(xp + 4); }
        uint4 pk;
        pk.x = (unsigned int)f2bf(f0.x) | ((unsigned int)f2bf(f0.y) << 16);
        pk.y = (unsigned int)f2bf(f0.z) | ((unsigned int)f2bf(f0.w) << 16);
        pk.z = (unsigned int)f2bf(f1.x) | ((unsigned int)f2bf(f1.y) << 16);
        pk.w = (unsigned int)f2bf(f1.z) | ((unsigned int)f2bf(f1.w) << 16);
        *(uint4*)&sm.Xs[0][sr >> 4][(sr & 15) + 16 * sk][0] = pk;
    }
    __syncthreads();

    for (int kt = 0; kt < 16; ++kt) {
        float4 g0 = {0, 0, 0, 0}, g1 = {0, 0, 0, 0};
        if (kt < 15 && svalid) {
            g0 = *(const float4*)(xp + (kt + 1) * 32);
            g1 = *(const float4*)(xp + (kt + 1) * 32 + 4);
        }

        short8 bf[2];
#pragma unroll
        for (int nf = 0; nf < 2; ++nf)
            bf[nf] = *(const short8*)(W1f + (((size_t)kt * 8 + wv * 2 + nf) * 64 + lane) * 8);
#pragma unroll
        for (int mf = 0; mf < 4; ++mf) {
            short8 af = *(const short8*)&sm.Xs[kt & 1][mf][lane][0];
#pragma unroll
            for (int nf = 0; nf < 2; ++nf)
                acc[mf][nf] = __builtin_amdgcn_mfma_f32_16x16x32_bf16(af, bf[nf], acc[mf][nf], 0, 0, 0);
        }

        if (kt < 15) {
            uint4 pk;
            pk.x = (unsigned int)f2bf(g0.x) | ((unsigned int)f2bf(g0.y) << 16);
            pk.y = (unsigned int)f2bf(g0.z) | ((unsigned int)f2bf(g0.w) << 16);
            pk.z = (unsigned int)f2bf(g1.x) | ((unsigned int)f2bf(g1.y) << 16);
            pk.w = (unsigned int)f2bf(g1.z) | ((unsigned int)f2bf(g1.w) << 16);
            *(uint4*)&sm.Xs[(kt + 1) & 1][sr >> 4][(sr & 15) + 16 * sk][0] = pk;
        }
        __syncthreads();
    }

    const int c0 = wv * 32 + (lane & 15);
    const float b1v0 = b1[c0];
    const float b1v1 = b1[c0 + 16];
#pragma unroll
    for (int mf = 0; mf < 4; ++mf) {
#pragma unroll
        for (int nf = 0; nf < 2; ++nf) {
            float bb = nf ? b1v1 : b1v0;
            int kk = nf * 16 + (lane & 15);
#pragma unroll
            for (int r = 0; r < 4; ++r) {
                int row = mf * 16 + 4 * (lane >> 4) + r;
                float h = fmaxf(acc[mf][nf][r] + bb, 0.0f);
                sm.HsP[wv][row][kk] = f2bf(h);
            }
        }
    }
    __syncthreads();

    f32x4 acc2[4];
#pragma unroll
    for (int mf = 0; mf < 4; ++mf) acc2[mf] = (f32x4){0.f, 0.f, 0.f, 0.f};
#pragma unroll
    for (int kt2 = 0; kt2 < 4; ++kt2) {
        short8 bf2 = *(const short8*)(W2f + (((size_t)kt2 * 4 + wv) * 64 + lane) * 8);
#pragma unroll
        for (int mf = 0; mf < 4; ++mf) {
            short8 af2 = *(const short8*)&sm.HsP[kt2][mf * 16 + (lane & 15)][8 * (lane >> 4)];
            acc2[mf] = __builtin_amdgcn_mfma_f32_16x16x32_bf16(af2, bf2, acc2[mf], 0, 0, 0);
        }
    }

    const int oc = wv * 16 + (lane & 15);
    const float bo = b2[oc];
#pragma unroll
    for (int mf = 0; mf < 4; ++mf) {
#pragma unroll
        for (int r = 0; r < 4; ++r) {
            long long row = (long long)bm0 + mf * 16 + 4 * (lane >> 4) + r;
            if (row < n) {
                float v = acc2[mf][r] + bo;
                ax0[row * 64 + oc] = f2bf(0.1f * v);
                float zv = dinv[row] * v * FP8_SCALE;
                unsigned int eb = __builtin_amdgcn_cvt_pk_fp8_f32(zv, zv, 0u, false) & 0xffu;
                zs0[row * 64 + oc] = (unsigned char)eb;
            }
        }
    }
}

// ---------------------------------------------------------------- propagation, fp8 state, rec-in-registers
// zs = fp8(16*dinv*z), [node][64] = 64 B rows. Wave = node.
// slot = lane>>3 (8 edge slots); lane&7 = 8-channel group (8 B).
// rec window (<=128 edges) prefetched into 2 VGPRs via coalesced loads;
// per-slot indices distributed with __shfl (lgkm, not vmcnt) -> gathers
// have NO memory dependency; 4 issued back-to-back per 32-edge chunk.
template<int LAST>
__global__ __launch_bounds__(256) void k_prop(const unsigned char* __restrict__ zs,
        const unsigned short* __restrict__ ax0, const int* __restrict__ rowptr,
        const int* __restrict__ rec, const float* __restrict__ dinv,
        unsigned char* __restrict__ zso, float* __restrict__ zfout, int n, int E) {
    int node = __builtin_amdgcn_readfirstlane(blockIdx.x * 4 + (threadIdx.x >> 6));
    if (node >= n) return;
    const int lane = threadIdx.x & 63;
    const int slot = lane >> 3;        // 8 edge slots
    const int cb   = (lane & 7) * 8;   // channel-group byte offset within 64-B row
    const int e0 = rowptr[node], e1 = rowptr[node + 1];

    // prefetch rec window into registers (coalesced; clamped addresses)
    const int rA = rec[min(e0 + lane, E - 1)];
    const int rB = rec[min(e0 + 64 + lane, E - 1)];

    float a0 = 0.f, a1 = 0.f, a2 = 0.f, a3 = 0.f;
    float a4 = 0.f, a5 = 0.f, a6 = 0.f, a7 = 0.f;

    const int ecap = min(e1, e0 + 128);
    int e = e0;
    // 32-edge chunks: 4 independent gathers in flight
    for (; e + 32 <= ecap; e += 32) {
        const int base = e - e0;            // multiple of 32: rA/rB select uniform
        int i0 = (base & 63) + slot;
        int r0, r1, r2, r3;
        if (base < 64) {
            r0 = __shfl(rA, i0, 64);      r1 = __shfl(rA, i0 + 8, 64);
            r2 = __shfl(rA, i0 + 16, 64); r3 = __shfl(rA, i0 + 24, 64);
        } else {
            r0 = __shfl(rB, i0, 64);      r1 = __shfl(rB, i0 + 8, 64);
            r2 = __shfl(rB, i0 + 16, 64); r3 = __shfl(rB, i0 + 24, 64);
        }
        uint2 d0 = *(const uint2*)(zs + (size_t)r0 + cb);
        uint2 d1 = *(const uint2*)(zs + (size_t)r1 + cb);
        uint2 d2 = *(const uint2*)(zs + (size_t)r2 + cb);
        uint2 d3 = *(const uint2*)(zs + (size_t)r3 + cb);
#define ACC8(d) { \
        f32x2 p0 = __builtin_amdgcn_cvt_pk_f32_fp8((d).x, false); \
        f32x2 p1 = __builtin_amdgcn_cvt_pk_f32_fp8((d).x, true);  \
        f32x2 p2 = __builtin_amdgcn_cvt_pk_f32_fp8((d).y, false); \
        f32x2 p3 = __builtin_amdgcn_cvt_pk_f32_fp8((d).y, true);  \
        a0 += p0.x; a1 += p0.y; a2 += p1.x; a3 += p1.y;           \
        a4 += p2.x; a5 += p2.y; a6 += p3.x; a7 += p3.y; }
        ACC8(d0) ACC8(d1) ACC8(d2) ACC8(d3)
    }
    // 8-edge steps from registers
    for (; e + 8 <= ecap; e += 8) {
        const int base = e - e0;            // multiple of 8; never straddles 64
        int idx = (base & 63) + slot;
        int rv = (base < 64) ? __shfl(rA, idx, 64) : __shfl(rB, idx, 64);
        uint2 d = *(const uint2*)(zs + (size_t)rv + cb);
        ACC8(d)
    }
    // memory fallback (deg > 128; effectively never for Poisson(32))
    for (; e + 8 <= e1; e += 8) {
        int r = rec[e + slot];
        uint2 d = *(const uint2*)(zs + (size_t)r + cb);
        ACC8(d)
    }
    // masked tail (< 8 edges)
    if (e < e1) {
        int ei = e + slot;
        int ec = (ei < e1) ? ei : (e1 - 1);
        int rv;
        if (ec - e0 < 128) {
            int idx = ((ec - e0) & 63) + 0;
            rv = (ec - e0 < 64) ? __shfl(rA, ec - e0, 64) : __shfl(rB, (ec - e0) & 63, 64);
        } else {
            rv = rec[ec];
        }
        uint2 d = *(const uint2*)(zs + (size_t)rv + cb);
        float w = (ei < e1) ? 1.f : 0.f;
        f32x2 p0 = __builtin_amdgcn_cvt_pk_f32_fp8(d.x, false);
        f32x2 p1 = __builtin_amdgcn_cvt_pk_f32_fp8(d.x, true);
        f32x2 p2 = __builtin_amdgcn_cvt_pk_f32_fp8(d.y, false);
        f32x2 p3 = __builtin_amdgcn_cvt_pk_f32_fp8(d.y, true);
        a0 = fmaf(w, p0.x, a0); a1 = fmaf(w, p0.y, a1);
        a2 = fmaf(w, p1.x, a2); a3 = fmaf(w, p1.y, a3);
        a4 = fmaf(w, p2.x, a4); a5 = fmaf(w, p2.y, a5);
        a6 = fmaf(w, p3.x, a6); a7 = fmaf(w, p3.y, a7);
    }
#undef ACC8

    // butterfly over slot bits (lane bits 3..5)
#pragma unroll
    for (int o = 8; o <= 32; o <<= 1) {
        a0 += __shfl_xor(a0, o, 64);
        a1 += __shfl_xor(a1, o, 64);
        a2 += __shfl_xor(a2, o, 64);
        a3 += __shfl_xor(a3, o, 64);
        a4 += __shfl_xor(a4, o, 64);
        a5 += __shfl_xor(a5, o, 64);
        a6 += __shfl_xor(a6, o, 64);
        a7 += __shfl_xor(a7, o, 64);
    }

    if (slot == 0) {                    // lanes 0..7 hold the full row sums
        // self loop
        uint2 ds = *(const uint2*)(zs + (size_t)node * 64 + cb);
        f32x2 s0 = __builtin_amdgcn_cvt_pk_f32_fp8(ds.x, false);
        f32x2 s1 = __builtin_amdgcn_cvt_pk_f32_fp8(ds.x, true);
        f32x2 s2 = __builtin_amdgcn_cvt_pk_f32_fp8(ds.y, false);
        f32x2 s3 = __builtin_amdgcn_cvt_pk_f32_fp8(ds.y, true);
        a0 += s0.x; a1 += s0.y; a2 += s1.x; a3 += s1.y;
        a4 += s2.x; a5 += s2.y; a6 += s3.x; a7 += s3.y;

        const float dv = dinv[node];
        const float c = 0.9f * dv * FP8_INV;
        uint4 da = *(const uint4*)((const char*)ax0 + (size_t)node * 128 + cb * 2);
        float z0 = fmaf(c, a0, ulo(da.x));
        float z1 = fmaf(c, a1, uhi(da.x));
        float z2 = fmaf(c, a2, ulo(da.y));
        float z3 = fmaf(c, a3, uhi(da.y));
        float z4 = fmaf(c, a4, ulo(da.z));
        float z5 = fmaf(c, a5, uhi(da.z));
        float z6 = fmaf(c, a6, ulo(da.w));
        float z7 = fmaf(c, a7, uhi(da.w));

        if (LAST) {
            float m = fmaxf(fmaxf(fmaxf(z0, z1), fmaxf(z2, z3)),
                            fmaxf(fmaxf(z4, z5), fmaxf(z6, z7)));
            m = fmaxf(m, __shfl_xor(m, 1, 64));
            m = fmaxf(m, __shfl_xor(m, 2, 64));
            m = fmaxf(m, __shfl_xor(m, 4, 64));
            float s = expf(z0 - m) + expf(z1 - m) + expf(z2 - m) + expf(z3 - m)
                    + expf(z4 - m) + expf(z5 - m) + expf(z6 - m) + expf(z7 - m);
            s += __shfl_xor(s, 1, 64);
            s += __shfl_xor(s, 2, 64);
            s += __shfl_xor(s, 4, 64);
            float ls = m + logf(s);
            float* dst = zfout + (size_t)node * 64 + cb;
            float4 o0 = {z0 - ls, z1 - ls, z2 - ls, z3 - ls};
            float4 o1 = {z4 - ls, z5 - ls, z6 - ls, z7 - ls};
            *(float4*)dst = o0;
            *(float4*)(dst + 4) = o1;
        } else {
            const float enc = FP8_SCALE * dv;
            unsigned int lo = __builtin_amdgcn_cvt_pk_fp8_f32(enc * z0, enc * z1, 0u, false);
            lo = __builtin_amdgcn_cvt_pk_fp8_f32(enc * z2, enc * z3, lo, true);
            unsigned int hi = __builtin_amdgcn_cvt_pk_fp8_f32(enc * z4, enc * z5, 0u, false);
            hi = __builtin_amdgcn_cvt_pk_fp8_f32(enc * z6, enc * z7, hi, true);
            uint2 pk; pk.x = lo; pk.y = hi;
            *(uint2*)(zso + (size_t)node * 64 + cb) = pk;
        }
    }
}

// ---------------------------------------------------------------- launch
extern "C" void kernel_launch(void* const* d_in, const int* in_sizes, int n_in,
                              void* d_out, int out_size, void* d_ws, size_t ws_size,
                              hipStream_t stream) {
    const float* x  = (const float*)d_in[0];
    const void*  ei = d_in[1];
    const float* W1 = (const float*)d_in[2];
    const float* b1 = (const float*)d_in[3];
    const float* W2 = (const float*)d_in[4];
    const float* b2 = (const float*)d_in[5];
    float* out = (float*)d_out;

    const int n = in_sizes[0] / 512;
    const int E = in_sizes[1] / 2;
    const int NB = (n + 255) >> 8;

    char* p = (char*)d_ws;
    auto alloc = [&](size_t bytes) {
        void* r = (void*)p;
        p += (bytes + 255) & ~(size_t)255;
        return r;
    };
    int*   rowptr  = (int*)alloc((size_t)(n + 1) * 4);
    int*   flag    = (int*)alloc(4);
    int*   bktcnt  = (int*)alloc(NBKT * 4);
    int*   bktbase = (int*)alloc((NBKT + 1) * 4);
    int*   bcur    = (int*)alloc(NBKT * 4);
    float* dinv    = (float*)alloc((size_t)n * 4);
    int*   rec     = (int*)alloc((size_t)E * 4);
    unsigned int* ebuf = (unsigned int*)alloc((size_t)E * 4);
    unsigned short* ax0 = (unsigned short*)alloc((size_t)n * 64 * 2);
    unsigned char* zsA = (unsigned char*)alloc((size_t)n * 64);
    unsigned char* zsB = (unsigned char*)alloc((size_t)n * 64);
    unsigned short* W1f = (unsigned short*)alloc(65536 * 2);
    unsigned short* W2f = (unsigned short*)alloc(8192 * 2);

    k_init<<<2, 256, 0, stream>>>(bktcnt, flag);
    k_detect<<<2, 256, 0, stream>>>((const int*)ei, E, flag);
    k_wprep<<<(65536 + 8192 + 255) / 256, 256, 0, stream>>>(W1, W2, W1f, W2f);
    k_bhist<<<512, 256, 0, stream>>>(ei, E, flag, bktcnt, n);
    k_bscan<<<1, 512, 0, stream>>>(bktcnt, bktbase, bcur, n);
    k_bucketA<<<512, 256, 0, stream>>>(ei, E, flag, bcur, ebuf, n);
    k_bucketB<<<NB, 256, 0, stream>>>(ebuf, bktbase, rowptr, rec, dinv, n);
    k_mlp<<<(n + 63) / 64, 256, 0, stream>>>(x, W1f, b1, W2f, b2, dinv, ax0, zsA, n);

    const unsigned char* zi = zsA;
    unsigned char* zo = zsB;
    for (int it = 0; it < KITER - 1; ++it) {
        k_prop<0><<<(n + 3) / 4, 256, 0, stream>>>(zi, ax0, rowptr, rec, dinv, zo, nullptr, n, E);
        const unsigned char* t = zi; zi = zo; zo = (unsigned char*)t;
    }
    k_prop<1><<<(n + 3) / 4, 256, 0, stream>>>(zi, ax0, rowptr, rec, dinv, nullptr, out, n, E);
}

// Round 12
// 740.498 us; speedup vs baseline: 3.8151x; 1.2680x over previous
//
#include <hip/hip_runtime.h>

#define KITER 16
#define NBKT 512   // max buckets (bucket = 256 target nodes); n <= 131072
#define FP8_SCALE 16.0f
#define FP8_INV   0.0625f

typedef __attribute__((ext_vector_type(8))) short short8;
typedef __attribute__((ext_vector_type(4))) float f32x4;
typedef __attribute__((ext_vector_type(2))) float f32x2;

__device__ __forceinline__ unsigned short f2bf(float f) {
    unsigned int u = __float_as_uint(f);
    u = (u + 0x7fffu + ((u >> 16) & 1u)) >> 16;
    return (unsigned short)u;
}
__device__ __forceinline__ float ulo(unsigned int d) {   // low bf16 -> f32
    return __uint_as_float(d << 16);
}
__device__ __forceinline__ float uhi(unsigned int d) {   // high bf16 -> f32
    return __uint_as_float(d & 0xffff0000u);
}

// ---------------------------------------------------------------- init
__global__ void k_init(int* bktcnt, int* flag) {
    int i = blockIdx.x * blockDim.x + threadIdx.x;
    if (i < NBKT) bktcnt[i] = 0;
    if (i == 0) *flag = 1;
}

// Detect int64 vs int32 edge_index
__global__ void k_detect(const int* ew, int e, int* flag) {
    int t = blockIdx.x * blockDim.x + threadIdx.x;
    if (t < 512 && t < e) {
        if (ew[2 * t + 1] != 0) atomicAnd(flag, 0);
    }
}

// ---------------------------------------------------------------- bucket histogram (LDS-staged)
__global__ __launch_bounds__(256) void k_bhist(const void* eptr, int E, const int* flag,
        int* bktcnt, int n) {
    __shared__ int h[NBKT];
    const int NB = (n + 255) >> 8;
    for (int i = threadIdx.x; i < NB; i += 256) h[i] = 0;
    __syncthreads();
    const int tid0 = blockIdx.x * 256 + threadIdx.x;
    const int stride = gridDim.x * 256;
    if (*flag) {
        const long long* pc = (const long long*)eptr + E;
        for (int i = tid0; i < E; i += stride) atomicAdd(&h[((int)pc[i]) >> 8], 1);
    } else {
        const int* pc = (const int*)eptr + E;
        for (int i = tid0; i < E; i += stride) atomicAdd(&h[pc[i] >> 8], 1);
    }
    __syncthreads();
    for (int i = threadIdx.x; i < NB; i += 256) if (h[i]) atomicAdd(&bktcnt[i], h[i]);
}

// ---------------------------------------------------------------- scan bucket totals -> bases
__global__ __launch_bounds__(512) void k_bscan(const int* bktcnt, int* bktbase, int* bcur, int n) {
    __shared__ int s[NBKT];
    const int NB = (n + 255) >> 8;
    const int tid = threadIdx.x;
    int v = (tid < NB) ? bktcnt[tid] : 0;
    s[tid] = v;
    __syncthreads();
    for (int off = 1; off < NBKT; off <<= 1) {
        int t = (tid >= off) ? s[tid - off] : 0;
        __syncthreads();
        s[tid] += t;
        __syncthreads();
    }
    int excl = s[tid] - v;
    if (tid < NB) { bktbase[tid] = excl; bcur[tid] = excl; }
    if (tid == NB - 1) bktbase[NB] = s[tid];
}

// ---------------------------------------------------------------- phase A: bucket partition
// ebuf entry: (src << 8) | (c & 255)
__global__ __launch_bounds__(256) void k_bucketA(const void* eptr, int E, const int* flag,
        int* bcur, unsigned int* ebuf, int n) {
    __shared__ int hist[NBKT];
    __shared__ int lbase[NBKT];
    __shared__ int lcur[NBKT];
    const int NB = (n + 255) >> 8;
    const int wg = blockIdx.x, nwg = gridDim.x, tid = threadIdx.x;
    const int s0 = (int)(((long long)E * wg) / nwg);
    const int s1 = (int)(((long long)E * (wg + 1)) / nwg);
    for (int b = tid; b < NB; b += 256) { hist[b] = 0; lcur[b] = 0; }
    __syncthreads();
    const bool w64 = (*flag != 0);
    if (w64) {
        const long long* pc = (const long long*)eptr + E;
        for (int i = s0 + tid; i < s1; i += 256)
            atomicAdd(&hist[((int)pc[i]) >> 8], 1);
    } else {
        const int* pc = (const int*)eptr + E;
        for (int i = s0 + tid; i < s1; i += 256)
            atomicAdd(&hist[pc[i] >> 8], 1);
    }
    __syncthreads();
    for (int b = tid; b < NB; b += 256)
        lbase[b] = hist[b] ? atomicAdd(&bcur[b], hist[b]) : 0;
    __syncthreads();
    if (w64) {
        const long long* ps = (const long long*)eptr;
        const long long* pc = ps + E;
        for (int i = s0 + tid; i < s1; i += 256) {
            int c = (int)pc[i];
            int s = (int)ps[i];
            int b = c >> 8;
            int pos = lbase[b] + atomicAdd(&lcur[b], 1);
            ebuf[pos] = ((unsigned int)s << 8) | (unsigned int)(c & 255);
        }
    } else {
        const int* ps = (const int*)eptr;
        const int* pc = ps + E;
        for (int i = s0 + tid; i < s1; i += 256) {
            int c = pc[i];
            int s = ps[i];
            int b = c >> 8;
            int pos = lbase[b] + atomicAdd(&lcur[b], 1);
            ebuf[pos] = ((unsigned int)s << 8) | (unsigned int)(c & 255);
        }
    }
}

// ---------------------------------------------------------------- phase B: within-bucket CSR + rowptr + dinv
// rec stores src*64 (byte offset of a [node][64] fp8 row).
__global__ __launch_bounds__(256) void k_bucketB(const unsigned int* ebuf, const int* bktbase,
        int* rowptr, int* rec, float* dinv, int n) {
    __shared__ int cnt[256];
    __shared__ int base[256];
    __shared__ int cur[256];
    const int NB = (n + 255) >> 8;
    const int b = blockIdx.x;
    const int lo = b << 8;
    const int nloc = min(256, n - lo);
    const int tid = threadIdx.x;
    cnt[tid] = 0; cur[tid] = 0;
    __syncthreads();
    const int e0 = bktbase[b], e1 = bktbase[b + 1];
    for (int i = e0 + tid; i < e1; i += 256)
        atomicAdd(&cnt[ebuf[i] & 255u], 1);
    __syncthreads();
    int v = cnt[tid];
    base[tid] = v;
    __syncthreads();
    for (int off = 1; off < 256; off <<= 1) {
        int t = (tid >= off) ? base[tid - off] : 0;
        __syncthreads();
        base[tid] += t;
        __syncthreads();
    }
    int ebase = e0 + base[tid] - v;
    if (tid < nloc) {
        rowptr[lo + tid] = ebase;
        dinv[lo + tid] = 1.0f / sqrtf((float)(v + 1));
    }
    base[tid] = ebase;
    __syncthreads();
    if (b == 0 && tid == 0) rowptr[n] = bktbase[NB];
    for (int i = e0 + tid; i < e1; i += 256) {
        unsigned int q = ebuf[i];
        int cl = (int)(q & 255u);
        int pos = base[cl] + atomicAdd(&cur[cl], 1);
        rec[pos] = (int)((q >> 8) << 6);   // src * 64 bytes (fp8 row)
    }
}

// ---------------------------------------------------------------- W1/W2 -> bf16 MFMA-fragment layout
__global__ void k_wprep(const float* __restrict__ W1, const float* __restrict__ W2,
                        unsigned short* __restrict__ W1f, unsigned short* __restrict__ W2f) {
    int t = blockIdx.x * 256 + threadIdx.x;
    if (t < 65536) {
        int e = t & 7, lane = (t >> 3) & 63, nf = (t >> 9) & 7, kt = t >> 12;
        int k = kt * 32 + 8 * (lane >> 4) + e;
        int nn = nf * 16 + (lane & 15);
        W1f[t] = f2bf(W1[k * 128 + nn]);
    } else if (t < 65536 + 8192) {
        int t2 = t - 65536;
        int e = t2 & 7, lane = (t2 >> 3) & 63, nf = (t2 >> 9) & 3, kt2 = t2 >> 11;
        int k = kt2 * 32 + 8 * (lane >> 4) + e;
        int nn = nf * 16 + (lane & 15);
        W2f[t2] = f2bf(W2[k * 64 + nn]);
    }
}

// ---------------------------------------------------------------- MFMA MLP: v = relu(x@W1+b1)@W2+b2
// Double-buffered X staging; emits ax0 = bf16(0.1*v) and zs0 = fp8(16*dinv*v).
__global__ __launch_bounds__(256) void k_mlp(const float* __restrict__ x,
        const unsigned short* __restrict__ W1f, const float* __restrict__ b1,
        const unsigned short* __restrict__ W2f, const float* __restrict__ b2,
        const float* __restrict__ dinv,
        unsigned short* __restrict__ ax0, unsigned char* __restrict__ zs0, int n) {
    __shared__ union {
        unsigned short Xs[2][4][64][8];   // 8 KB  (A-frags, double-buffered)
        unsigned short HsP[4][64][40];    // 20 KB (h, padded 80-B rows)
    } sm;

    const int tid  = threadIdx.x;
    const int lane = tid & 63;
    const int wv   = tid >> 6;
    const int bm0  = blockIdx.x * 64;

    const int sr = tid >> 2;
    const int sk = tid & 3;
    const long long srow = (long long)bm0 + sr;
    const bool svalid = srow < n;
    const float* xp = x + srow * 512 + sk * 8;

    f32x4 acc[4][2];
#pragma unroll
    for (int mf = 0; mf < 4; ++mf)
#pragma unroll
        for (int nf = 0; nf < 2; ++nf) acc[mf][nf] = (f32x4){0.f, 0.f, 0.f, 0.f};

    {
        float4 f0 = {0, 0, 0, 0}, f1 = {0, 0, 0, 0};
        if (svalid) { f0 = *(const float4*)(xp); f1 = *(const float4*)(xp + 4); }
        uint4 pk;
        pk.x = (unsigned int)f2bf(f0.x) | ((unsigned int)f2bf(f0.y) << 16);
        pk.y = (unsigned int)f2bf(f0.z) | ((unsigned int)f2bf(f0.w) << 16);
        pk.z = (unsigned int)f2bf(f1.x) | ((unsigned int)f2bf(f1.y) << 16);
        pk.w = (unsigned int)f2bf(f1.z) | ((unsigned int)f2bf(f1.w) << 16);
        *(uint4*)&sm.Xs[0][sr >> 4][(sr & 15) + 16 * sk][0] = pk;
    }
    __syncthreads();

    for (int kt = 0; kt < 16; ++kt) {
        float4 g0 = {0, 0, 0, 0}, g1 = {0, 0, 0, 0};
        if (kt < 15 && svalid) {
            g0 = *(const float4*)(xp + (kt + 1) * 32);
            g1 = *(const float4*)(xp + (kt + 1) * 32 + 4);
        }

        short8 bf[2];
#pragma unroll
        for (int nf = 0; nf < 2; ++nf)
            bf[nf] = *(const short8*)(W1f + (((size_t)kt * 8 + wv * 2 + nf) * 64 + lane) * 8);
#pragma unroll
        for (int mf = 0; mf < 4; ++mf) {
            short8 af = *(const short8*)&sm.Xs[kt & 1][mf][lane][0];
#pragma unroll
            for (int nf = 0; nf < 2; ++nf)
                acc[mf][nf] = __builtin_amdgcn_mfma_f32_16x16x32_bf16(af, bf[nf], acc[mf][nf], 0, 0, 0);
        }

        if (kt < 15) {
            uint4 pk;
            pk.x = (unsigned int)f2bf(g0.x) | ((unsigned int)f2bf(g0.y) << 16);
            pk.y = (unsigned int)f2bf(g0.z) | ((unsigned int)f2bf(g0.w) << 16);
            pk.z = (unsigned int)f2bf(g1.x) | ((unsigned int)f2bf(g1.y) << 16);
            pk.w = (unsigned int)f2bf(g1.z) | ((unsigned int)f2bf(g1.w) << 16);
            *(uint4*)&sm.Xs[(kt + 1) & 1][sr >> 4][(sr & 15) + 16 * sk][0] = pk;
        }
        __syncthreads();
    }

    const int c0 = wv * 32 + (lane & 15);
    const float b1v0 = b1[c0];
    const float b1v1 = b1[c0 + 16];
#pragma unroll
    for (int mf = 0; mf < 4; ++mf) {
#pragma unroll
        for (int nf = 0; nf < 2; ++nf) {
            float bb = nf ? b1v1 : b1v0;
            int kk = nf * 16 + (lane & 15);
#pragma unroll
            for (int r = 0; r < 4; ++r) {
                int row = mf * 16 + 4 * (lane >> 4) + r;
                float h = fmaxf(acc[mf][nf][r] + bb, 0.0f);
                sm.HsP[wv][row][kk] = f2bf(h);
            }
        }
    }
    __syncthreads();

    f32x4 acc2[4];
#pragma unroll
    for (int mf = 0; mf < 4; ++mf) acc2[mf] = (f32x4){0.f, 0.f, 0.f, 0.f};
#pragma unroll
    for (int kt2 = 0; kt2 < 4; ++kt2) {
        short8 bf2 = *(const short8*)(W2f + (((size_t)kt2 * 4 + wv) * 64 + lane) * 8);
#pragma unroll
        for (int mf = 0; mf < 4; ++mf) {
            short8 af2 = *(const short8*)&sm.HsP[kt2][mf * 16 + (lane & 15)][8 * (lane >> 4)];
            acc2[mf] = __builtin_amdgcn_mfma_f32_16x16x32_bf16(af2, bf2, acc2[mf], 0, 0, 0);
        }
    }

    const int oc = wv * 16 + (lane & 15);
    const float bo = b2[oc];
#pragma unroll
    for (int mf = 0; mf < 4; ++mf) {
#pragma unroll
        for (int r = 0; r < 4; ++r) {
            long long row = (long long)bm0 + mf * 16 + 4 * (lane >> 4) + r;
            if (row < n) {
                float v = acc2[mf][r] + bo;
                ax0[row * 64 + oc] = f2bf(0.1f * v);
                float zv = dinv[row] * v * FP8_SCALE;
                unsigned int eb = __builtin_amdgcn_cvt_pk_fp8_f32(zv, zv, 0u, false) & 0xffu;
                zs0[row * 64 + oc] = (unsigned char)eb;
            }
        }
    }
}

// ---------------------------------------------------------------- propagation: 2 nodes/wave, fp8 state, rec-in-registers
// zs = fp8(16*dinv*z), [node][64] = 64 B rows.
// Lanes 0-31 = node A, 32-63 = node B. slot4 = (lane&31)>>3 (4 edge slots/node);
// lane&7 = 8-channel group. rec window (64 edges/node) in rA/rB via 2 coalesced
// loads; shfl distribution stays within each half. All chunks masked; dead-lane
// addresses clamp to row 0 (hot line) so masked chunks add no line traffic.
template<int LAST>
__global__ __launch_bounds__(256) void k_prop(const unsigned char* __restrict__ zs,
        const unsigned short* __restrict__ ax0, const int* __restrict__ rowptr,
        const int* __restrict__ rec, const float* __restrict__ dinv,
        unsigned char* __restrict__ zso, float* __restrict__ zfout, int n, int E) {
    const int lane  = threadIdx.x & 63;
    const int hl    = lane & 31;
    const int node  = min(blockIdx.x * 8 + (threadIdx.x >> 6) * 2 + (lane >> 5), n - 1);
    const int slot4 = hl >> 3;          // 4 edge slots per node
    const int cb    = (lane & 7) * 8;   // channel-group byte offset within 64-B row

    const int e0 = rowptr[node];
    const int e1 = rowptr[node + 1];

    // prefetch 64-edge window per node (2 coalesced loads cover both halves)
    const int rA = rec[min(e0 + hl, E - 1)];
    const int rB = rec[min(e0 + 32 + hl, E - 1)];

    float a0 = 0.f, a1 = 0.f, a2 = 0.f, a3 = 0.f;
    float a4 = 0.f, a5 = 0.f, a6 = 0.f, a7 = 0.f;

#define ACCW(d, w) { \
    f32x2 p0 = __builtin_amdgcn_cvt_pk_f32_fp8((d).x, false); \
    f32x2 p1 = __builtin_amdgcn_cvt_pk_f32_fp8((d).x, true);  \
    f32x2 p2 = __builtin_amdgcn_cvt_pk_f32_fp8((d).y, false); \
    f32x2 p3 = __builtin_amdgcn_cvt_pk_f32_fp8((d).y, true);  \
    a0 = fmaf(w, p0.x, a0); a1 = fmaf(w, p0.y, a1);           \
    a2 = fmaf(w, p1.x, a2); a3 = fmaf(w, p1.y, a3);           \
    a4 = fmaf(w, p2.x, a4); a5 = fmaf(w, p2.y, a5);           \
    a6 = fmaf(w, p3.x, a6); a7 = fmaf(w, p3.y, a7); }

    const int ecap = min(e1, e0 + 64);
    int e = e0;
    for (; e < ecap; e += 16) {          // masked 16-edge chunks (uniform per half)
        const int b = e - e0;            // multiple of 16, 0..48
        int rsrc = (b >= 32) ? rB : rA;  // uniform per half; source lanes agree
        int ibase = (lane & 32) + (b & 31) + slot4;
        int r0 = __shfl(rsrc, ibase, 64);
        int r1 = __shfl(rsrc, ibase + 4, 64);
        int r2 = __shfl(rsrc, ibase + 8, 64);
        int r3 = __shfl(rsrc, ibase + 12, 64);
        bool k0 = (e + slot4      < e1), k1 = (e + 4 + slot4  < e1);
        bool k2 = (e + 8 + slot4  < e1), k3 = (e + 12 + slot4 < e1);
        r0 = k0 ? r0 : 0; r1 = k1 ? r1 : 0;   // dead lanes hit hot row 0
        r2 = k2 ? r2 : 0; r3 = k3 ? r3 : 0;
        uint2 d0 = *(const uint2*)(zs + (size_t)r0 + cb);
        uint2 d1 = *(const uint2*)(zs + (size_t)r1 + cb);
        uint2 d2 = *(const uint2*)(zs + (size_t)r2 + cb);
        uint2 d3 = *(const uint2*)(zs + (size_t)r3 + cb);
        ACCW(d0, k0 ? 1.f : 0.f)
        ACCW(d1, k1 ? 1.f : 0.f)
        ACCW(d2, k2 ? 1.f : 0.f)
        ACCW(d3, k3 ? 1.f : 0.f)
    }
    // fallback for deg > 64 (essentially never for Poisson(32))
    for (; e < e1; e += 4) {
        int ei = e + slot4;
        bool ok = ei < e1;
        int r = rec[min(ei, e1 - 1)];
        uint2 d = *(const uint2*)(zs + (size_t)(ok ? r : 0) + cb);
        ACCW(d, ok ? 1.f : 0.f)
    }
#undef ACCW

    // butterfly over slot bits (lane bits 3..4) within each 32-lane half
#pragma unroll
    for (int o = 8; o <= 16; o <<= 1) {
        a0 += __shfl_xor(a0, o, 64);
        a1 += __shfl_xor(a1, o, 64);
        a2 += __shfl_xor(a2, o, 64);
        a3 += __shfl_xor(a3, o, 64);
        a4 += __shfl_xor(a4, o, 64);
        a5 += __shfl_xor(a5, o, 64);
        a6 += __shfl_xor(a6, o, 64);
        a7 += __shfl_xor(a7, o, 64);
    }

    if (hl < 8) {                        // 8 writer lanes per node
        // self loop
        uint2 ds = *(const uint2*)(zs + (size_t)node * 64 + cb);
        f32x2 s0 = __builtin_amdgcn_cvt_pk_f32_fp8(ds.x, false);
        f32x2 s1 = __builtin_amdgcn_cvt_pk_f32_fp8(ds.x, true);
        f32x2 s2 = __builtin_amdgcn_cvt_pk_f32_fp8(ds.y, false);
        f32x2 s3 = __builtin_amdgcn_cvt_pk_f32_fp8(ds.y, true);
        a0 += s0.x; a1 += s0.y; a2 += s1.x; a3 += s1.y;
        a4 += s2.x; a5 += s2.y; a6 += s3.x; a7 += s3.y;

        const float dv = dinv[node];
        const float c = 0.9f * dv * FP8_INV;
        uint4 da = *(const uint4*)((const char*)ax0 + (size_t)node * 128 + cb * 2);
        float z0 = fmaf(c, a0, ulo(da.x));
        float z1 = fmaf(c, a1, uhi(da.x));
        float z2 = fmaf(c, a2, ulo(da.y));
        float z3 = fmaf(c, a3, uhi(da.y));
        float z4 = fmaf(c, a4, ulo(da.z));
        float z5 = fmaf(c, a5, uhi(da.z));
        float z6 = fmaf(c, a6, ulo(da.w));
        float z7 = fmaf(c, a7, uhi(da.w));

        if (LAST) {
            float m = fmaxf(fmaxf(fmaxf(z0, z1), fmaxf(z2, z3)),
                            fmaxf(fmaxf(z4, z5), fmaxf(z6, z7)));
            m = fmaxf(m, __shfl_xor(m, 1, 64));
            m = fmaxf(m, __shfl_xor(m, 2, 64));
            m = fmaxf(m, __shfl_xor(m, 4, 64));
            float s = expf(z0 - m) + expf(z1 - m) + expf(z2 - m) + expf(z3 - m)
                    + expf(z4 - m) + expf(z5 - m) + expf(z6 - m) + expf(z7 - m);
            s += __shfl_xor(s, 1, 64);
            s += __shfl_xor(s, 2, 64);
            s += __shfl_xor(s, 4, 64);
            float ls = m + logf(s);
            float* dst = zfout + (size_t)node * 64 + cb;
            float4 o0 = {z0 - ls, z1 - ls, z2 - ls, z3 - ls};
            float4 o1 = {z4 - ls, z5 - ls, z6 - ls, z7 - ls};
            *(float4*)dst = o0;
            *(float4*)(dst + 4) = o1;
        } else {
            const float enc = FP8_SCALE * dv;
            unsigned int lo = __builtin_amdgcn_cvt_pk_fp8_f32(enc * z0, enc * z1, 0u, false);
            lo = __builtin_amdgcn_cvt_pk_fp8_f32(enc * z2, enc * z3, lo, true);
            unsigned int hi = __builtin_amdgcn_cvt_pk_fp8_f32(enc * z4, enc * z5, 0u, false);
            hi = __builtin_amdgcn_cvt_pk_fp8_f32(enc * z6, enc * z7, hi, true);
            uint2 pk; pk.x = lo; pk.y = hi;
            *(uint2*)(zso + (size_t)node * 64 + cb) = pk;
        }
    }
}

// ---------------------------------------------------------------- launch
extern "C" void kernel_launch(void* const* d_in, const int* in_sizes, int n_in,
                              void* d_out, int out_size, void* d_ws, size_t ws_size,
                              hipStream_t stream) {
    const float* x  = (const float*)d_in[0];
    const void*  ei = d_in[1];
    const float* W1 = (const float*)d_in[2];
    const float* b1 = (const float*)d_in[3];
    const float* W2 = (const float*)d_in[4];
    const float* b2 = (const float*)d_in[5];
    float* out = (float*)d_out;

    const int n = in_sizes[0] / 512;
    const int E = in_sizes[1] / 2;
    const int NB = (n + 255) >> 8;

    char* p = (char*)d_ws;
    auto alloc = [&](size_t bytes) {
        void* r = (void*)p;
        p += (bytes + 255) & ~(size_t)255;
        return r;
    };
    int*   rowptr  = (int*)alloc((size_t)(n + 1) * 4);
    int*   flag    = (int*)alloc(4);
    int*   bktcnt  = (int*)alloc(NBKT * 4);
    int*   bktbase = (int*)alloc((NBKT + 1) * 4);
    int*   bcur    = (int*)alloc(NBKT * 4);
    float* dinv    = (float*)alloc((size_t)n * 4);
    int*   rec     = (int*)alloc((size_t)E * 4);
    unsigned int* ebuf = (unsigned int*)alloc((size_t)E * 4);
    unsigned short* ax0 = (unsigned short*)alloc((size_t)n * 64 * 2);
    unsigned char* zsA = (unsigned char*)alloc((size_t)n * 64);
    unsigned char* zsB = (unsigned char*)alloc((size_t)n * 64);
    unsigned short* W1f = (unsigned short*)alloc(65536 * 2);
    unsigned short* W2f = (unsigned short*)alloc(8192 * 2);

    k_init<<<2, 256, 0, stream>>>(bktcnt, flag);
    k_detect<<<2, 256, 0, stream>>>((const int*)ei, E, flag);
    k_wprep<<<(65536 + 8192 + 255) / 256, 256, 0, stream>>>(W1, W2, W1f, W2f);
    k_bhist<<<512, 256, 0, stream>>>(ei, E, flag, bktcnt, n);
    k_bscan<<<1, 512, 0, stream>>>(bktcnt, bktbase, bcur, n);
    k_bucketA<<<512, 256, 0, stream>>>(ei, E, flag, bcur, ebuf, n);
    k_bucketB<<<NB, 256, 0, stream>>>(ebuf, bktbase, rowptr, rec, dinv, n);
    k_mlp<<<(n + 63) / 64, 256, 0, stream>>>(x, W1f, b1, W2f, b2, dinv, ax0, zsA, n);

    const unsigned char* zi = zsA;
    unsigned char* zo = zsB;
    for (int it = 0; it < KITER - 1; ++it) {
        k_prop<0><<<(n + 7) / 8, 256, 0, stream>>>(zi, ax0, rowptr, rec, dinv, zo, nullptr, n, E);
        const unsigned char* t = zi; zi = zo; zo = (unsigned char*)t;
    }
    k_prop<1><<<(n + 7) / 8, 256, 0, stream>>>(zi, ax0, rowptr, rec, dinv, nullptr, out, n, E);
}